// Round 1
// baseline (113.436 us; speedup 1.0000x reference)
//
#include <hip/hip_runtime.h>

// VQ-VAE quantization, R10. MI355X gfx950.
// x: [131072, 64] f32; emb: [512, 64] f32.
// d_out: quantized_st [8388608] | loss [1] | perplexity [1].
//
// R10 structural change: vq_final is gone. Histogram accumulates into a
// global u32[512] via device-scope atomics (zeroed in vq_prep); the last
// block to finish (atomic ticket) computes perplexity + final loss scale.
// Argmin no longer carries the per-row x-norm (constant offset, cannot
// change argmin); prep stores 1+||e||^2 so scores stay in (0.7,1.3) and a
// u32 pack (score_bits & ~0x1FF | code) gives a 3-VALU-per-code min:
// 9 dropped mantissa bits = 6e-5 quantization, 300x below the ~0.018
// inter-code spread and below the tolerated 3e-4 bf16 score error.
//
// Rows-per-wave: each wave owns 32 rows x all 512 codes; bf16 codebook in
// LDS (64KB, fragment order) -> 2 blocks/CU, 16 waves/CU.

#define D      64
#define M      512
#define N_VEC  131072
#define N_ELEM 8388608

typedef __attribute__((ext_vector_type(8))) short short8;
typedef __attribute__((ext_vector_type(4))) float f32x4;

// ws bytes: [0,4) loss f32 | [32,36) ticket u32 | [64,2112) bnorm f32[512]
//   (bnorm[c] = 1 + ||emb[c]||^2)
// | [4096, 4096+65536) bf16 e-plane (h only) in FRAGMENT order:
//   element (ct,s,lane,j) at ((ct*2+s)*64+lane)*8+j
//   holding bf16(emb[ct*16 + (lane&15)][s*32 + (lane>>4)*8 + j])
// | [131072, 131072+2048) u32 global histogram [512]

static __device__ __forceinline__ unsigned short f2bf(float f) {
    unsigned u = __float_as_uint(f);
    return (unsigned short)((u + 0x7FFFu + ((u >> 16) & 1u)) >> 16);  // RNE
}

// ---- e-side prep: bf16 plane (frag order) + (1+norm) + zero {loss, ticket,
//      ghist}. grid 16 x 256.
__global__ __launch_bounds__(256)
void vq_prep(const float* __restrict__ emb, float* __restrict__ bnorm,
             unsigned short* __restrict__ planes, float* __restrict__ loss_sum,
             unsigned* __restrict__ ticket, unsigned* __restrict__ ghist) {
    const int g = blockIdx.x * 256 + threadIdx.x;   // 4096 tasks = 512 codes x 8 (s,q)
    if (g == 0) { *loss_sum = 0.f; *ticket = 0u; }
    if (g < M) ghist[g] = 0u;

    const int c = g >> 3, s = (g >> 2) & 1, q = g & 3;
    const float* e = emb + c * D + s * 32 + q * 8;
    short8 h;
#pragma unroll
    for (int j = 0; j < 8; ++j) h[j] = (short)f2bf(e[j]);
    const int ct = c >> 4, col = c & 15;
    *(short8*)(planes + ((ct * 2 + s) * 64 + q * 16 + col) * 8) = h;

    if ((g & 7) == 0) {            // one thread per code: exact sequential norm tree
        const float* ec = emb + c * D;
        float s0 = 0.f, s1 = 0.f, s2 = 0.f, s3 = 0.f;
        for (int k = 0; k < D; k += 4) {
            float e0 = ec[k], e1 = ec[k + 1], e2 = ec[k + 2], e3 = ec[k + 3];
            s0 = fmaf(e0, e0, s0); s1 = fmaf(e1, e1, s1);
            s2 = fmaf(e2, e2, s2); s3 = fmaf(e3, e3, s3);
        }
        bnorm[c] = 1.0f + ((s0 + s1) + (s2 + s3));   // +1: keep packed scores > 0
    }
}

__global__ __launch_bounds__(512, 4)   // 8 waves/block, 4 waves/EU -> 2 blocks/CU
void vq_main(const float* __restrict__ x, const float* __restrict__ emb,
             const float* __restrict__ bnorm, const unsigned short* __restrict__ planes,
             float* __restrict__ out, float* __restrict__ loss_sum,
             unsigned* __restrict__ ticket, unsigned* __restrict__ ghist) {
    __shared__ __align__(16) short sE[32768];   // 64 KB bf16 codebook, frag order
    __shared__ float sBn[M];                    // 1 + ||e||^2
    __shared__ unsigned sCode[256];
    __shared__ unsigned sHist[M];
    __shared__ float sRed[8];
    __shared__ unsigned sLast;

    const int tid = threadIdx.x;
    const int w = tid >> 6, lane = tid & 63;
    const int q = lane >> 4, col = lane & 15;
    const int rowBase = blockIdx.x * 256 + w * 32;   // wave-private 32 rows

    // ---- stage codebook plane -> LDS (coalesced), norms, zero hist ----
    {
        const short8* src = (const short8*)planes;   // 4096 short8s
        short8* dst = (short8*)sE;
#pragma unroll
        for (int k = 0; k < 8; ++k) dst[tid + k * 512] = src[tid + k * 512];
        sBn[tid] = bnorm[tid];
        sHist[tid] = 0u;
    }

    // ---- x rows (A-frag pattern: lane holds row=col / 16+col, k = s*32+q*8+j) ----
    float4 xc[8];
    {
        const float* p0 = x + (size_t)(rowBase + col) * D + q * 8;
        const float* p1 = x + (size_t)(rowBase + 16 + col) * D + q * 8;
        xc[0] = *(const float4*)(p0);      xc[1] = *(const float4*)(p0 + 4);
        xc[2] = *(const float4*)(p0 + 32); xc[3] = *(const float4*)(p0 + 36);
        xc[4] = *(const float4*)(p1);      xc[5] = *(const float4*)(p1 + 4);
        xc[6] = *(const float4*)(p1 + 32); xc[7] = *(const float4*)(p1 + 36);
    }

    // ---- bf16 x-frags (single plane). No x-norm: it is a per-row constant
    //      offset to every score and cannot change the argmin. ----
    short8 XH[2][2];
#pragma unroll
    for (int p = 0; p < 2; ++p) {
        float f[16] = {xc[p*4+0].x, xc[p*4+0].y, xc[p*4+0].z, xc[p*4+0].w,
                       xc[p*4+1].x, xc[p*4+1].y, xc[p*4+1].z, xc[p*4+1].w,
                       xc[p*4+2].x, xc[p*4+2].y, xc[p*4+2].z, xc[p*4+2].w,
                       xc[p*4+3].x, xc[p*4+3].y, xc[p*4+3].z, xc[p*4+3].w};
#pragma unroll
        for (int j = 0; j < 8; ++j) {
            XH[p][0][j] = (short)f2bf(f[j]);
            XH[p][1][j] = (short)f2bf(f[8 + j]);
        }
    }

    __syncthreads();   // barrier 1: sE/sBn/sHist visible

    // ---- all 32 code-tiles: A=codes (LDS frags), B=x (regs), 4 MFMA/tile.
    //      score = (1+Bn) - 2*dot in (0.7,1.3); packed u32 min:
    //      (bits & ~0x1FF) | code  -> ascending scan keeps first-argmin ties ----
    unsigned best0 = 0xFFFFFFFFu, best1 = 0xFFFFFFFFu;
#pragma unroll 4
    for (int t = 0; t < 32; ++t) {
        const int fb = t * 1024 + lane * 8;   // shorts
        short8 Eh0 = *(const short8*)&sE[fb];
        short8 Eh1 = *(const short8*)&sE[fb + 512];
        f32x4 Bn4 = *(const f32x4*)&sBn[t * 16 + q * 4];

        f32x4 a1 = {0.f, 0.f, 0.f, 0.f};
        a1 = __builtin_amdgcn_mfma_f32_16x16x32_bf16(Eh0, XH[0][0], a1, 0, 0, 0);
        a1 = __builtin_amdgcn_mfma_f32_16x16x32_bf16(Eh1, XH[0][1], a1, 0, 0, 0);
        f32x4 b1 = {0.f, 0.f, 0.f, 0.f};
        b1 = __builtin_amdgcn_mfma_f32_16x16x32_bf16(Eh0, XH[1][0], b1, 0, 0, 0);
        b1 = __builtin_amdgcn_mfma_f32_16x16x32_bf16(Eh1, XH[1][1], b1, 0, 0, 0);

        const int cb = t * 16 + q * 4;
#pragma unroll
        for (int r = 0; r < 4; ++r) {
            float sc0 = fmaf(-2.0f, a1[r], Bn4[r]);
            float sc1 = fmaf(-2.0f, b1[r], Bn4[r]);
            unsigned p0 = (__float_as_uint(sc0) & 0xFFFFFE00u) | (unsigned)(cb + r);
            unsigned p1 = (__float_as_uint(sc1) & 0xFFFFFE00u) | (unsigned)(cb + r);
            best0 = p0 < best0 ? p0 : best0;
            best1 = p1 < best1 ? p1 : best1;
        }
    }

    // ---- cross-q reduce (u32 min; scores > 0 so uint order == float order) ----
    {
        unsigned o;
        o = __shfl_xor(best0, 16, 64); best0 = o < best0 ? o : best0;
        o = __shfl_xor(best0, 32, 64); best0 = o < best0 ? o : best0;
        o = __shfl_xor(best1, 16, 64); best1 = o < best1 ? o : best1;
        o = __shfl_xor(best1, 32, 64); best1 = o < best1 ? o : best1;
    }
    if (q == 0) {   // winners for rows w*32+col and w*32+16+col
        const unsigned c0 = best0 & 511u, c1 = best1 & 511u;
        sCode[w * 32 + col] = c0;
        sCode[w * 32 + 16 + col] = c1;
        atomicAdd(&sHist[c0], 1u);
        atomicAdd(&sHist[c1], 1u);
    }

    // ---- epilogue: wave-private 32 rows, coalesced (same-wave LDS RAW on
    //      sCode is waitcnt-ordered, no barrier needed) ----
    float lacc = 0.f;
#pragma unroll 2
    for (int i = 0; i < 8; ++i) {
        const int rr = i * 4 + q;            // 0..31
        const unsigned code = sCode[w * 32 + rr];
        const size_t a = (size_t)(rowBase + rr) * D + col * 4;
        const float4 xv = *(const float4*)(x + a);       // L1/L2-warm
        const float4 qv = *(const float4*)(emb + (size_t)code * D + col * 4);
        const float e0 = xv.x - qv.x, e1 = xv.y - qv.y, e2 = xv.z - qv.z, e3 = xv.w - qv.w;
        lacc = fmaf(e0, e0, lacc); lacc = fmaf(e1, e1, lacc);
        lacc = fmaf(e2, e2, lacc); lacc = fmaf(e3, e3, lacc);
        float4 o;  // out = fl(x + fl(q - x)) == fl(x - fl(x - q)) bit-exactly
        o.x = xv.x - e0; o.y = xv.y - e1; o.z = xv.z - e2; o.w = xv.w - e3;
        *(float4*)(out + a) = o;
    }
#pragma unroll
    for (int off = 32; off > 0; off >>= 1) lacc += __shfl_down(lacc, off, 64);
    if (lane == 0) sRed[w] = lacc;
    __syncthreads();   // barrier 2: sHist + sRed complete

    // ---- merge block hist into global (device-scope atomics), block loss ----
    {
        const unsigned h = sHist[tid];
        if (h) atomicAdd(&ghist[tid], h);
    }
    if (tid == 0) {
        float s = ((sRed[0] + sRed[1]) + (sRed[2] + sRed[3]))
                + ((sRed[4] + sRed[5]) + (sRed[6] + sRed[7]));
        atomicAdd(loss_sum, s);
    }
    __syncthreads();   // barrier 3: drains vmcnt(0) -> all hist atomics executed

    if (tid == 0) {
        __threadfence();                      // order loss atomic before ticket
        sLast = (atomicAdd(ticket, 1u) == 511u) ? 1u : 0u;
    }
    __syncthreads();   // barrier 4: sLast visible (uniform)

    if (sLast) {
        // ---- last block: perplexity + final loss (device otherwise idle).
        //      Reads via atomic RMW -> coherence point, immune to stale L2. ----
        const unsigned cnt = atomicAdd(&ghist[tid], 0u);
        const float p = (float)cnt * (1.0f / 131072.0f);
        float term = p * logf(p + 1e-10f);
#pragma unroll
        for (int off = 32; off > 0; off >>= 1) term += __shfl_down(term, off, 64);
        if (lane == 0) sRed[w] = term;
        __syncthreads();
        if (tid == 0) {
            float s = 0.f;
#pragma unroll
            for (int ww = 0; ww < 8; ++ww) s += sRed[ww];
            const float L = atomicAdd(loss_sum, 0.0f);   // total incl. own block
            out[N_ELEM]     = 0.25f * (L * (1.0f / 8388608.0f));
            out[N_ELEM + 1] = expf(-s);
        }
    }
}

extern "C" void kernel_launch(void* const* d_in, const int* in_sizes, int n_in,
                              void* d_out, int out_size, void* d_ws, size_t ws_size,
                              hipStream_t stream) {
    (void)in_sizes; (void)n_in; (void)out_size; (void)ws_size;
    const float* x   = (const float*)d_in[0];
    const float* emb = (const float*)d_in[1];
    float* out = (float*)d_out;

    float*          loss   = (float*)d_ws;
    unsigned*       ticket = (unsigned*)((char*)d_ws + 32);
    float*          bnorm  = (float*)((char*)d_ws + 64);
    unsigned short* plns   = (unsigned short*)((char*)d_ws + 4096);
    unsigned*       ghist  = (unsigned*)((char*)d_ws + 131072);

    vq_prep<<<dim3(16), dim3(256), 0, stream>>>(emb, bnorm, plns, loss, ticket, ghist);
    vq_main<<<dim3(512), dim3(512), 0, stream>>>(x, emb, bnorm, plns, out, loss,
                                                 ticket, ghist);
}